// Round 5
// baseline (266.251 us; speedup 1.0000x reference)
//
#include <hip/hip_runtime.h>
#include <math.h>

#define NN 10000
#define NE 100000
#define BN_EPS 1e-5f

// ---------------------------------------------------------------------------
// K0: prep. Pre-transpose weights, zero out + BN-stat accumulators.
//  wT0[i*320+c]: c<256 -> w0[(i*32+(c&31))*8+(c>>5)]; c<288 -> b0; else root0
//  wT1[i*640+c]: c<512 -> w1[(i*64+(c&63))*8+(c>>6)]; c<576 -> b1; else root1
//  wstT[i*256+o]: o<128 -> s_w[o,i]; else t_w[o-128,i]
// ---------------------------------------------------------------------------
__global__ __launch_bounds__(256) void k_prep(
    const float* __restrict__ w0, const float* __restrict__ b0,
    const float* __restrict__ root0,
    const float* __restrict__ w1, const float* __restrict__ b1,
    const float* __restrict__ root1,
    const float* __restrict__ s_w, const float* __restrict__ t_w,
    float* __restrict__ wT0, float* __restrict__ wT1, float* __restrict__ wstT,
    float* __restrict__ st0, float* __restrict__ st1, float* __restrict__ out)
{
  int gid = blockIdx.x * 256 + threadIdx.x;
  int gsz = gridDim.x * 256;
  for (int idx = gid; idx < 16 * 320; idx += gsz) {
    int i = idx / 320, c = idx - i * 320;
    float v;
    if (c < 256)      v = w0[(i * 32 + (c & 31)) * 8 + (c >> 5)];
    else if (c < 288) v = b0[i * 32 + (c - 256)];
    else              v = root0[i * 32 + (c - 288)];
    wT0[idx] = v;
  }
  for (int idx = gid; idx < 32 * 640; idx += gsz) {
    int i = idx / 640, c = idx - i * 640;
    float v;
    if (c < 512)      v = w1[(i * 64 + (c & 63)) * 8 + (c >> 6)];
    else if (c < 576) v = b1[i * 64 + (c - 512)];
    else              v = root1[i * 64 + (c - 576)];
    wT1[idx] = v;
  }
  for (int idx = gid; idx < 64 * 256; idx += gsz) {
    int i = idx >> 8, o = idx & 255;
    wstT[idx] = (o < 128) ? s_w[o * 64 + i] : t_w[(o - 128) * 64 + i];
  }
  for (int idx = gid; idx < 64 * 128; idx += gsz) out[idx] = 0.f;
  if (gid < 64)  st0[gid] = 0.f;
  if (gid < 128) st1[gid] = 0.f;
}

// ---------------------------------------------------------------------------
// S1: CSR cursor build in ONE block: LDS histogram of src + parallel scan.
// 1024 threads, 40KB LDS. cursor[n] = exclusive prefix of degree(n).
// ---------------------------------------------------------------------------
__global__ __launch_bounds__(1024) void k_csr(
    const int* __restrict__ ei, int* __restrict__ cursor)
{
  __shared__ int hist[NN];
  __shared__ int wsum[16];
  int tid = threadIdx.x;
  for (int i = tid; i < NN; i += 1024) hist[i] = 0;
  __syncthreads();
  for (int e = tid; e < NE; e += 1024) atomicAdd(&hist[ei[e]], 1);
  __syncthreads();
  int base = tid * 10;
  int s = 0;
#pragma unroll
  for (int j = 0; j < 10; ++j) {
    int idx = base + j;
    if (idx < NN) s += hist[idx];
  }
  int own = s;
  // inclusive scan within each wave
  for (int off = 1; off < 64; off <<= 1) {
    int t = __shfl_up(s, off, 64);
    if ((tid & 63) >= off) s += t;
  }
  if ((tid & 63) == 63) wsum[tid >> 6] = s;
  __syncthreads();
  if (tid < 16) {
    int v = wsum[tid];
    for (int off = 1; off < 16; off <<= 1) {
      int t = __shfl_up(v, off, 64);
      if (tid >= off) v += t;
    }
    wsum[tid] = v;  // inclusive wave sums
  }
  __syncthreads();
  int wv = tid >> 6;
  int run = s - own + (wv ? wsum[wv - 1] : 0);  // exclusive prefix at `base`
  for (int j = 0; j < 10; ++j) {
    int idx = base + j;
    if (idx < NN) { cursor[idx] = run; run += hist[idx]; }
  }
}

// ---------------------------------------------------------------------------
// S2: scatter edges into src-sorted arrays (srcS, dstS, eaS).
// ---------------------------------------------------------------------------
__global__ __launch_bounds__(256) void k_scatter(
    const int* __restrict__ ei, const float* __restrict__ ea,
    int* __restrict__ cursor, int* __restrict__ srcS, int* __restrict__ dstS,
    float* __restrict__ eaS)
{
  int e = blockIdx.x * 256 + threadIdx.x;
  if (e >= NE) return;
  int src = ei[e];
  int p = atomicAdd(&cursor[src], 1);
  srcS[p] = src;
  dstS[p] = ei[NE + e];
  const float4* ev = (const float4*)(ea + 8 * (size_t)e);
  float4 a = ev[0], b = ev[1];
  float4* ov = (float4*)(eaS + 8 * (size_t)p);
  ov[0] = a; ov[1] = b;
}

// ---------------------------------------------------------------------------
// K1: layer-0 node kernel, register-column GEMV (thread c owns column c).
// ---------------------------------------------------------------------------
__global__ __launch_bounds__(320) void k_node0(
    const float* __restrict__ x, const float* __restrict__ wT0,
    const float* __restrict__ bias0,
    float* __restrict__ G0, float* __restrict__ h0)
{
  int c = threadIdx.x;
  float wc[16];
#pragma unroll
  for (int i = 0; i < 16; ++i) wc[i] = wT0[i * 320 + c];
  float bi = (c >= 288) ? bias0[c - 288] : 0.f;

  int n0 = blockIdx.x * 20;
  for (int n = n0; n < n0 + 20; n += 2) {
    const float4* xa = (const float4*)(x + n * 16);
    float a0 = 0.f, a1 = 0.f;
#pragma unroll
    for (int q = 0; q < 4; ++q) {
      float4 v0 = xa[q], v1 = xa[q + 4];
      a0 = fmaf(v0.x, wc[4 * q + 0], a0); a1 = fmaf(v1.x, wc[4 * q + 0], a1);
      a0 = fmaf(v0.y, wc[4 * q + 1], a0); a1 = fmaf(v1.y, wc[4 * q + 1], a1);
      a0 = fmaf(v0.z, wc[4 * q + 2], a0); a1 = fmaf(v1.z, wc[4 * q + 2], a1);
      a0 = fmaf(v0.w, wc[4 * q + 3], a0); a1 = fmaf(v1.w, wc[4 * q + 3], a1);
    }
    if (c < 288) {
      G0[n * 288 + c]       = a0;
      G0[(n + 1) * 288 + c] = a1;
    } else {
      h0[n * 32 + (c - 288)]       = a0 + bi;
      h0[(n + 1) * 32 + (c - 288)] = a1 + bi;
    }
  }
}

// ---------------------------------------------------------------------------
// K2: layer-0 edge kernel, chunked src-sorted. Wave = 32-edge chunk; halves
// take alternating edges; G row reloaded only on src change (sorted => rare).
// ---------------------------------------------------------------------------
__global__ __launch_bounds__(256) void k_edge0c(
    const int* __restrict__ srcS, const int* __restrict__ dstS,
    const float* __restrict__ eaS,
    const float* __restrict__ G0, float* __restrict__ h0)
{
  int tid = threadIdx.x;
  int lane = tid & 63;
  int o = lane & 31, ph = lane >> 5;
  int w = blockIdx.x * 4 + (tid >> 6);
  int p0 = w * 32;
  if (p0 >= NE) return;
  int p1 = p0 + 32; if (p1 > NE) p1 = NE;
  int scur = -1;
  float g[8] = {0,0,0,0,0,0,0,0};
  float gb = 0.f;
  for (int p = p0 + ph; p < p1; p += 2) {
    int s = srcS[p];
    if (s != scur) {
      const float* gr = G0 + (size_t)s * 288;
#pragma unroll
      for (int k = 0; k < 8; ++k) g[k] = gr[k * 32 + o];
      gb = gr[256 + o];
      scur = s;
    }
    int dst = dstS[p];
    const float4* ev = (const float4*)(eaS + 8 * (size_t)p);
    float4 e0 = ev[0], e1 = ev[1];
    float m = gb;
    m = fmaf(e0.x, g[0], m); m = fmaf(e0.y, g[1], m);
    m = fmaf(e0.z, g[2], m); m = fmaf(e0.w, g[3], m);
    m = fmaf(e1.x, g[4], m); m = fmaf(e1.y, g[5], m);
    m = fmaf(e1.z, g[6], m); m = fmaf(e1.w, g[7], m);
    unsafeAtomicAdd(&h0[(size_t)dst * 32 + o], m);
  }
}

// ---------------------------------------------------------------------------
// K3/K6: per-column sum & sumsq over N rows (BN stats), atomic partials.
// ---------------------------------------------------------------------------
template <int C>
__global__ __launch_bounds__(256) void k_stats(
    const float* __restrict__ h, float* __restrict__ st)
{
  const int RPB = 256 / C;
  int tid = threadIdx.x;
  int col = tid % C, rg = tid / C;
  float s1 = 0.f, s2 = 0.f;
  int step = gridDim.x * RPB;
  for (int n = blockIdx.x * RPB + rg; n < NN; n += step) {
    float v = h[n * C + col];
    s1 += v; s2 += v * v;
  }
  __shared__ float l1[256], l2[256];
  l1[tid] = s1; l2[tid] = s2;
  __syncthreads();
  if (tid < C) {
    for (int r = 1; r < RPB; ++r) { s1 += l1[r * C + tid]; s2 += l2[r * C + tid]; }
    unsafeAtomicAdd(&st[tid], s1);
    unsafeAtomicAdd(&st[C + tid], s2);
  }
}

// ---------------------------------------------------------------------------
// K4: layer-1 node kernel with FUSED BN0+ReLU (reads raw h0 + st0).
// Thread t owns output columns {2t, 2t+1} in 64 weight VGPRs.
// ---------------------------------------------------------------------------
__global__ __launch_bounds__(320) void k_node1(
    const float* __restrict__ h0, const float* __restrict__ st0,
    const float* __restrict__ gamma0, const float* __restrict__ beta0,
    const float* __restrict__ wT1, const float* __restrict__ bias1,
    float* __restrict__ G1, float* __restrict__ h1)
{
  __shared__ float sc[32], sh[32];
  int t = threadIdx.x;
  if (t < 32) {
    float mu  = st0[t] * (1.0f / NN);
    float var = st0[32 + t] * (1.0f / NN) - mu * mu;
    float s   = gamma0[t] * rsqrtf(var + BN_EPS);
    sc[t] = s;
    sh[t] = beta0[t] - mu * s;
  }
  __syncthreads();

  float wa[32], wb[32];
#pragma unroll
  for (int i = 0; i < 32; ++i) {
    float2 w2 = *(const float2*)(wT1 + i * 640 + 2 * t);
    wa[i] = w2.x; wb[i] = w2.y;
  }
  float bia = 0.f, bib = 0.f;
  if (t >= 288) { bia = bias1[2 * (t - 288)]; bib = bias1[2 * (t - 288) + 1]; }

  int n0 = blockIdx.x * 20;
  for (int n = n0; n < n0 + 20; n += 2) {
    const float4* xa = (const float4*)(h0 + n * 32);
    float a00 = 0.f, a01 = 0.f, a10 = 0.f, a11 = 0.f;
#pragma unroll
    for (int q = 0; q < 8; ++q) {
      float4 v0 = xa[q], v1 = xa[q + 8];  // rows n and n+1, cols 4q..4q+3
      float c0 = sc[4 * q], c1 = sc[4 * q + 1], c2 = sc[4 * q + 2], c3 = sc[4 * q + 3];
      float d0 = sh[4 * q], d1 = sh[4 * q + 1], d2 = sh[4 * q + 2], d3 = sh[4 * q + 3];
      v0.x = fmaxf(fmaf(v0.x, c0, d0), 0.f); v1.x = fmaxf(fmaf(v1.x, c0, d0), 0.f);
      v0.y = fmaxf(fmaf(v0.y, c1, d1), 0.f); v1.y = fmaxf(fmaf(v1.y, c1, d1), 0.f);
      v0.z = fmaxf(fmaf(v0.z, c2, d2), 0.f); v1.z = fmaxf(fmaf(v1.z, c2, d2), 0.f);
      v0.w = fmaxf(fmaf(v0.w, c3, d3), 0.f); v1.w = fmaxf(fmaf(v1.w, c3, d3), 0.f);
      a00 = fmaf(v0.x, wa[4 * q + 0], a00); a01 = fmaf(v0.x, wb[4 * q + 0], a01);
      a00 = fmaf(v0.y, wa[4 * q + 1], a00); a01 = fmaf(v0.y, wb[4 * q + 1], a01);
      a00 = fmaf(v0.z, wa[4 * q + 2], a00); a01 = fmaf(v0.z, wb[4 * q + 2], a01);
      a00 = fmaf(v0.w, wa[4 * q + 3], a00); a01 = fmaf(v0.w, wb[4 * q + 3], a01);
      a10 = fmaf(v1.x, wa[4 * q + 0], a10); a11 = fmaf(v1.x, wb[4 * q + 0], a11);
      a10 = fmaf(v1.y, wa[4 * q + 1], a10); a11 = fmaf(v1.y, wb[4 * q + 1], a11);
      a10 = fmaf(v1.z, wa[4 * q + 2], a10); a11 = fmaf(v1.z, wb[4 * q + 2], a11);
      a10 = fmaf(v1.w, wa[4 * q + 3], a10); a11 = fmaf(v1.w, wb[4 * q + 3], a11);
    }
    if (t < 288) {
      *(float2*)(G1 + n * 576 + 2 * t)       = make_float2(a00, a01);
      *(float2*)(G1 + (n + 1) * 576 + 2 * t) = make_float2(a10, a11);
    } else {
      int o = 2 * (t - 288);
      *(float2*)(h1 + n * 64 + o)       = make_float2(a00 + bia, a01 + bib);
      *(float2*)(h1 + (n + 1) * 64 + o) = make_float2(a10 + bia, a11 + bib);
    }
  }
}

// ---------------------------------------------------------------------------
// K5: layer-1 edge kernel, chunked src-sorted. Wave = 16-edge chunk; G row
// (64 cols x 9) in VGPRs, reloaded only on src change.
// ---------------------------------------------------------------------------
__global__ __launch_bounds__(256) void k_edge1c(
    const int* __restrict__ srcS, const int* __restrict__ dstS,
    const float* __restrict__ eaS,
    const float* __restrict__ G1, float* __restrict__ h1)
{
  int tid = threadIdx.x;
  int o = tid & 63;
  int w = blockIdx.x * 4 + (tid >> 6);
  int p0 = w * 16;
  if (p0 >= NE) return;
  int p1 = p0 + 16; if (p1 > NE) p1 = NE;
  int scur = -1;
  float g[8] = {0,0,0,0,0,0,0,0};
  float gb = 0.f;
  for (int p = p0; p < p1; ++p) {
    int s = srcS[p];
    if (s != scur) {
      const float* gr = G1 + (size_t)s * 576;
#pragma unroll
      for (int k = 0; k < 8; ++k) g[k] = gr[k * 64 + o];
      gb = gr[512 + o];
      scur = s;
    }
    int dst = dstS[p];
    const float4* ev = (const float4*)(eaS + 8 * (size_t)p);
    float4 e0 = ev[0], e1 = ev[1];
    float m = gb;
    m = fmaf(e0.x, g[0], m); m = fmaf(e0.y, g[1], m);
    m = fmaf(e0.z, g[2], m); m = fmaf(e0.w, g[3], m);
    m = fmaf(e1.x, g[4], m); m = fmaf(e1.y, g[5], m);
    m = fmaf(e1.z, g[6], m); m = fmaf(e1.w, g[7], m);
    unsafeAtomicAdd(&h1[(size_t)dst * 64 + o], m);
  }
}

// ---------------------------------------------------------------------------
// K7: head with FUSED BN1+ReLU (reads raw h1 + st1). Thread c (0..127 per
// 2-wave group) owns output column c in regs. Sorted batch -> per-thread
// accumulator, one atomic per boundary.
// ---------------------------------------------------------------------------
__global__ __launch_bounds__(256) void k_head(
    const float* __restrict__ h1, const float* __restrict__ st1,
    const float* __restrict__ gamma1, const float* __restrict__ beta1,
    const float* __restrict__ wstT, const float* __restrict__ s_b,
    const float* __restrict__ t_b, const int* __restrict__ batch,
    float* __restrict__ out)
{
  __shared__ float sc[64], sh[64];
  int tid = threadIdx.x;
  if (tid < 64) {
    float mu  = st1[tid] * (1.0f / NN);
    float var = st1[64 + tid] * (1.0f / NN) - mu * mu;
    float s   = gamma1[tid] * rsqrtf(var + BN_EPS);
    sc[tid] = s;
    sh[tid] = beta1[tid] - mu * s;
  }
  __syncthreads();

  int c = tid & 127, g = tid >> 7;
  int n0 = blockIdx.x * 40 + g * 20;
  int n1 = n0 + 20;
  if (n0 >= NN) return;
  if (n1 > NN) n1 = NN;

  float wsr[64], wtr[64];
#pragma unroll
  for (int k = 0; k < 64; ++k) {
    wsr[k] = wstT[k * 256 + c];
    wtr[k] = wstT[k * 256 + 128 + c];
  }
  float sb = s_b[c], tb = t_b[c];

  int bcur = batch[n0];
  float facc = 0.f;
  for (int n = n0; n < n1; ++n) {
    const float4* xr = (const float4*)(h1 + (size_t)n * 64);
    float as = 0.f, at = 0.f;
#pragma unroll
    for (int q = 0; q < 16; ++q) {
      float4 xv = xr[q];
      xv.x = fmaxf(fmaf(xv.x, sc[4 * q],     sh[4 * q]),     0.f);
      xv.y = fmaxf(fmaf(xv.y, sc[4 * q + 1], sh[4 * q + 1]), 0.f);
      xv.z = fmaxf(fmaf(xv.z, sc[4 * q + 2], sh[4 * q + 2]), 0.f);
      xv.w = fmaxf(fmaf(xv.w, sc[4 * q + 3], sh[4 * q + 3]), 0.f);
      as = fmaf(xv.x, wsr[4 * q + 0], as); at = fmaf(xv.x, wtr[4 * q + 0], at);
      as = fmaf(xv.y, wsr[4 * q + 1], as); at = fmaf(xv.y, wtr[4 * q + 1], at);
      as = fmaf(xv.z, wsr[4 * q + 2], as); at = fmaf(xv.z, wtr[4 * q + 2], at);
      as = fmaf(xv.w, wsr[4 * q + 3], as); at = fmaf(xv.w, wtr[4 * q + 3], at);
    }
    float sv = fminf(30.f, fmaxf(-30.f, as + sb));
    float tv = at + tb;
    float f  = tanhf(tv) / (1.f + expf(sv));
    int b = batch[n];
    if (b != bcur) {
      unsafeAtomicAdd(&out[bcur * 128 + c], facc);
      bcur = b; facc = 0.f;
    }
    facc += f;
  }
  unsafeAtomicAdd(&out[bcur * 128 + c], facc);
}

// ---------------------------------------------------------------------------
extern "C" void kernel_launch(void* const* d_in, const int* in_sizes, int n_in,
                              void* d_out, int out_size, void* d_ws, size_t ws_size,
                              hipStream_t stream)
{
  const float* x     = (const float*)d_in[0];
  const int*   ei    = (const int*)d_in[1];
  const float* ea    = (const float*)d_in[2];
  const int*   batch = (const int*)d_in[3];
  // d_in[4] edge_batch: unused by the reference
  const float* w0    = (const float*)d_in[5];
  const float* b0    = (const float*)d_in[6];
  const float* root0 = (const float*)d_in[7];
  const float* bias0 = (const float*)d_in[8];
  const float* g0    = (const float*)d_in[9];
  const float* be0   = (const float*)d_in[10];
  const float* w1    = (const float*)d_in[11];
  const float* b1    = (const float*)d_in[12];
  const float* root1 = (const float*)d_in[13];
  const float* bias1 = (const float*)d_in[14];
  const float* g1    = (const float*)d_in[15];
  const float* be1   = (const float*)d_in[16];
  const float* s_w   = (const float*)d_in[17];
  const float* s_b   = (const float*)d_in[18];
  const float* t_w   = (const float*)d_in[19];
  const float* t_b   = (const float*)d_in[20];
  float* out = (float*)d_out;

  float* ws   = (float*)d_ws;
  float* G0   = ws;  ws += 2880000;   // N*288
  float* G1   = ws;  ws += 5760000;   // N*576
  float* h0   = ws;  ws += 320000;    // N*32
  float* h1   = ws;  ws += 640000;    // N*64
  float* st0  = ws;  ws += 64;
  float* st1  = ws;  ws += 128;
  float* wstT = ws;  ws += 16384;     // 64x256 transposed head weights
  float* wT0  = ws;  ws += 5120;      // 16x320
  float* wT1  = ws;  ws += 20480;     // 32x640
  float* eaS  = ws;  ws += 800000;    // E*8 src-sorted edge attrs
  int*   iw   = (int*)ws;
  int* cursor = iw;  iw += NN;
  int* srcS   = iw;  iw += NE;
  int* dstS   = iw;  iw += NE;

  hipLaunchKernelGGL(k_prep, dim3(64), dim3(256), 0, stream,
                     w0, b0, root0, w1, b1, root1, s_w, t_w,
                     wT0, wT1, wstT, st0, st1, out);
  hipLaunchKernelGGL(k_csr, dim3(1), dim3(1024), 0, stream, ei, cursor);
  hipLaunchKernelGGL(k_scatter, dim3((NE + 255) / 256), dim3(256), 0, stream,
                     ei, ea, cursor, srcS, dstS, eaS);
  hipLaunchKernelGGL(k_node0, dim3(500), dim3(320), 0, stream,
                     x, wT0, bias0, G0, h0);
  hipLaunchKernelGGL(k_edge0c, dim3((NE / 32 + 3) / 4), dim3(256), 0, stream,
                     srcS, dstS, eaS, G0, h0);
  hipLaunchKernelGGL(k_stats<32>, dim3(64), dim3(256), 0, stream, h0, st0);
  hipLaunchKernelGGL(k_node1, dim3(500), dim3(320), 0, stream,
                     h0, st0, g0, be0, wT1, bias1, G1, h1);
  hipLaunchKernelGGL(k_edge1c, dim3((NE / 16 + 3) / 4), dim3(256), 0, stream,
                     srcS, dstS, eaS, G1, h1);
  hipLaunchKernelGGL(k_stats<64>, dim3(128), dim3(256), 0, stream, h1, st1);
  hipLaunchKernelGGL(k_head, dim3(250), dim3(256), 0, stream,
                     h1, st1, g1, be1, wstT, s_b, t_b, batch, out);
}

// Round 6
// 261.008 us; speedup vs baseline: 1.0201x; 1.0201x over previous
//
#include <hip/hip_runtime.h>
#include <math.h>

#define NN 10000
#define NE 100000
#define BN_EPS 1e-5f

// ---------------------------------------------------------------------------
// K0: prep. Pre-transpose weights, zero out + BN-stat accumulators + deg.
//  wT0[i*320+c]: c<256 -> w0[(i*32+(c&31))*8+(c>>5)]; c<288 -> b0; else root0
//  wT1[i*640+c]: c<512 -> w1[(i*64+(c&63))*8+(c>>6)]; c<576 -> b1; else root1
//  wstT[i*256+o]: o<128 -> s_w[o,i]; else t_w[o-128,i]
// ---------------------------------------------------------------------------
__global__ __launch_bounds__(256) void k_prep(
    const float* __restrict__ w0, const float* __restrict__ b0,
    const float* __restrict__ root0,
    const float* __restrict__ w1, const float* __restrict__ b1,
    const float* __restrict__ root1,
    const float* __restrict__ s_w, const float* __restrict__ t_w,
    float* __restrict__ wT0, float* __restrict__ wT1, float* __restrict__ wstT,
    float* __restrict__ st0, float* __restrict__ st1, float* __restrict__ out,
    int* __restrict__ deg)
{
  int gid = blockIdx.x * 256 + threadIdx.x;
  int gsz = gridDim.x * 256;
  for (int idx = gid; idx < 16 * 320; idx += gsz) {
    int i = idx / 320, c = idx - i * 320;
    float v;
    if (c < 256)      v = w0[(i * 32 + (c & 31)) * 8 + (c >> 5)];
    else if (c < 288) v = b0[i * 32 + (c - 256)];
    else              v = root0[i * 32 + (c - 288)];
    wT0[idx] = v;
  }
  for (int idx = gid; idx < 32 * 640; idx += gsz) {
    int i = idx / 640, c = idx - i * 640;
    float v;
    if (c < 512)      v = w1[(i * 64 + (c & 63)) * 8 + (c >> 6)];
    else if (c < 576) v = b1[i * 64 + (c - 512)];
    else              v = root1[i * 64 + (c - 576)];
    wT1[idx] = v;
  }
  for (int idx = gid; idx < 64 * 256; idx += gsz) {
    int i = idx >> 8, o = idx & 255;
    wstT[idx] = (o < 128) ? s_w[o * 64 + i] : t_w[(o - 128) * 64 + i];
  }
  for (int idx = gid; idx < 64 * 128; idx += gsz) out[idx] = 0.f;
  for (int idx = gid; idx < NN; idx += gsz) deg[idx] = 0;
  if (gid < 64)  st0[gid] = 0.f;
  if (gid < 128) st1[gid] = 0.f;
}

// ---------------------------------------------------------------------------
// K1: layer-0 node kernel + parallel degree histogram (independent block
// ranges in ONE launch). Blocks 0..499: register-column GEMV (thread c owns
// column c). Blocks 500..599: grid-stride histogram of src over deg[].
// ---------------------------------------------------------------------------
__global__ __launch_bounds__(320) void k_node0hist(
    const float* __restrict__ x, const float* __restrict__ wT0,
    const float* __restrict__ bias0,
    float* __restrict__ G0, float* __restrict__ h0,
    const int* __restrict__ ei, int* __restrict__ deg)
{
  if (blockIdx.x >= 500) {
    int t = (blockIdx.x - 500) * 320 + threadIdx.x;
    for (int e = t; e < NE; e += 100 * 320) atomicAdd(&deg[ei[e]], 1);
    return;
  }
  int c = threadIdx.x;
  float wc[16];
#pragma unroll
  for (int i = 0; i < 16; ++i) wc[i] = wT0[i * 320 + c];
  float bi = (c >= 288) ? bias0[c - 288] : 0.f;

  int n0 = blockIdx.x * 20;
  for (int n = n0; n < n0 + 20; n += 2) {
    const float4* xa = (const float4*)(x + n * 16);
    float a0 = 0.f, a1 = 0.f;
#pragma unroll
    for (int q = 0; q < 4; ++q) {
      float4 v0 = xa[q], v1 = xa[q + 4];
      a0 = fmaf(v0.x, wc[4 * q + 0], a0); a1 = fmaf(v1.x, wc[4 * q + 0], a1);
      a0 = fmaf(v0.y, wc[4 * q + 1], a0); a1 = fmaf(v1.y, wc[4 * q + 1], a1);
      a0 = fmaf(v0.z, wc[4 * q + 2], a0); a1 = fmaf(v1.z, wc[4 * q + 2], a1);
      a0 = fmaf(v0.w, wc[4 * q + 3], a0); a1 = fmaf(v1.w, wc[4 * q + 3], a1);
    }
    if (c < 288) {
      G0[n * 288 + c]       = a0;
      G0[(n + 1) * 288 + c] = a1;
    } else {
      h0[n * 32 + (c - 288)]       = a0 + bi;
      h0[(n + 1) * 32 + (c - 288)] = a1 + bi;
    }
  }
}

// ---------------------------------------------------------------------------
// S1: exclusive scan of deg -> cursor. Single block, 256 threads, ~3 us.
// ---------------------------------------------------------------------------
__global__ __launch_bounds__(256) void k_scan(
    const int* __restrict__ deg, int* __restrict__ cursor)
{
  __shared__ int part[256];
  int t = threadIdx.x;
  int base = t * 40;
  int s = 0;
#pragma unroll 8
  for (int j = 0; j < 40; ++j) {
    int idx = base + j;
    if (idx < NN) s += deg[idx];
  }
  part[t] = s;
  __syncthreads();
  if (t == 0) {
    int r = 0;
    for (int i = 0; i < 256; ++i) { int v = part[i]; part[i] = r; r += v; }
  }
  __syncthreads();
  int r = part[t];
  for (int j = 0; j < 40; ++j) {
    int idx = base + j;
    if (idx < NN) { cursor[idx] = r; r += deg[idx]; }
  }
}

// ---------------------------------------------------------------------------
// S2: scatter edges into src-sorted arrays (srcS, dstS, eaS).
// ---------------------------------------------------------------------------
__global__ __launch_bounds__(256) void k_scatter(
    const int* __restrict__ ei, const float* __restrict__ ea,
    int* __restrict__ cursor, int* __restrict__ srcS, int* __restrict__ dstS,
    float* __restrict__ eaS)
{
  int e = blockIdx.x * 256 + threadIdx.x;
  if (e >= NE) return;
  int src = ei[e];
  int p = atomicAdd(&cursor[src], 1);
  srcS[p] = src;
  dstS[p] = ei[NE + e];
  const float4* ev = (const float4*)(ea + 8 * (size_t)e);
  float4 a = ev[0], b = ev[1];
  float4* ov = (float4*)(eaS + 8 * (size_t)p);
  ov[0] = a; ov[1] = b;
}

// ---------------------------------------------------------------------------
// K2: layer-0 edge kernel, chunked src-sorted. Wave = 32-edge chunk; halves
// take alternating edges; G row reloaded only on src change (sorted => rare).
// ---------------------------------------------------------------------------
__global__ __launch_bounds__(256) void k_edge0c(
    const int* __restrict__ srcS, const int* __restrict__ dstS,
    const float* __restrict__ eaS,
    const float* __restrict__ G0, float* __restrict__ h0)
{
  int tid = threadIdx.x;
  int lane = tid & 63;
  int o = lane & 31, ph = lane >> 5;
  int w = blockIdx.x * 4 + (tid >> 6);
  int p0 = w * 32;
  if (p0 >= NE) return;
  int p1 = p0 + 32; if (p1 > NE) p1 = NE;
  int scur = -1;
  float g[8] = {0,0,0,0,0,0,0,0};
  float gb = 0.f;
  for (int p = p0 + ph; p < p1; p += 2) {
    int s = srcS[p];
    if (s != scur) {
      const float* gr = G0 + (size_t)s * 288;
#pragma unroll
      for (int k = 0; k < 8; ++k) g[k] = gr[k * 32 + o];
      gb = gr[256 + o];
      scur = s;
    }
    int dst = dstS[p];
    const float4* ev = (const float4*)(eaS + 8 * (size_t)p);
    float4 e0 = ev[0], e1 = ev[1];
    float m = gb;
    m = fmaf(e0.x, g[0], m); m = fmaf(e0.y, g[1], m);
    m = fmaf(e0.z, g[2], m); m = fmaf(e0.w, g[3], m);
    m = fmaf(e1.x, g[4], m); m = fmaf(e1.y, g[5], m);
    m = fmaf(e1.z, g[6], m); m = fmaf(e1.w, g[7], m);
    unsafeAtomicAdd(&h0[(size_t)dst * 32 + o], m);
  }
}

// ---------------------------------------------------------------------------
// K3/K6: per-column sum & sumsq over N rows (BN stats), atomic partials.
// ---------------------------------------------------------------------------
template <int C>
__global__ __launch_bounds__(256) void k_stats(
    const float* __restrict__ h, float* __restrict__ st)
{
  const int RPB = 256 / C;
  int tid = threadIdx.x;
  int col = tid % C, rg = tid / C;
  float s1 = 0.f, s2 = 0.f;
  int step = gridDim.x * RPB;
  for (int n = blockIdx.x * RPB + rg; n < NN; n += step) {
    float v = h[n * C + col];
    s1 += v; s2 += v * v;
  }
  __shared__ float l1[256], l2[256];
  l1[tid] = s1; l2[tid] = s2;
  __syncthreads();
  if (tid < C) {
    for (int r = 1; r < RPB; ++r) { s1 += l1[r * C + tid]; s2 += l2[r * C + tid]; }
    unsafeAtomicAdd(&st[tid], s1);
    unsafeAtomicAdd(&st[C + tid], s2);
  }
}

// ---------------------------------------------------------------------------
// K4: layer-1 node kernel with FUSED BN0+ReLU (reads raw h0 + st0).
// Thread t owns output columns {2t, 2t+1} in 64 weight VGPRs.
// ---------------------------------------------------------------------------
__global__ __launch_bounds__(320) void k_node1(
    const float* __restrict__ h0, const float* __restrict__ st0,
    const float* __restrict__ gamma0, const float* __restrict__ beta0,
    const float* __restrict__ wT1, const float* __restrict__ bias1,
    float* __restrict__ G1, float* __restrict__ h1)
{
  __shared__ float sc[32], sh[32];
  int t = threadIdx.x;
  if (t < 32) {
    float mu  = st0[t] * (1.0f / NN);
    float var = st0[32 + t] * (1.0f / NN) - mu * mu;
    float s   = gamma0[t] * rsqrtf(var + BN_EPS);
    sc[t] = s;
    sh[t] = beta0[t] - mu * s;
  }
  __syncthreads();

  float wa[32], wb[32];
#pragma unroll
  for (int i = 0; i < 32; ++i) {
    float2 w2 = *(const float2*)(wT1 + i * 640 + 2 * t);
    wa[i] = w2.x; wb[i] = w2.y;
  }
  float bia = 0.f, bib = 0.f;
  if (t >= 288) { bia = bias1[2 * (t - 288)]; bib = bias1[2 * (t - 288) + 1]; }

  int n0 = blockIdx.x * 20;
  for (int n = n0; n < n0 + 20; n += 2) {
    const float4* xa = (const float4*)(h0 + n * 32);
    float a00 = 0.f, a01 = 0.f, a10 = 0.f, a11 = 0.f;
#pragma unroll
    for (int q = 0; q < 8; ++q) {
      float4 v0 = xa[q], v1 = xa[q + 8];  // rows n and n+1, cols 4q..4q+3
      float c0 = sc[4 * q], c1 = sc[4 * q + 1], c2 = sc[4 * q + 2], c3 = sc[4 * q + 3];
      float d0 = sh[4 * q], d1 = sh[4 * q + 1], d2 = sh[4 * q + 2], d3 = sh[4 * q + 3];
      v0.x = fmaxf(fmaf(v0.x, c0, d0), 0.f); v1.x = fmaxf(fmaf(v1.x, c0, d0), 0.f);
      v0.y = fmaxf(fmaf(v0.y, c1, d1), 0.f); v1.y = fmaxf(fmaf(v1.y, c1, d1), 0.f);
      v0.z = fmaxf(fmaf(v0.z, c2, d2), 0.f); v1.z = fmaxf(fmaf(v1.z, c2, d2), 0.f);
      v0.w = fmaxf(fmaf(v0.w, c3, d3), 0.f); v1.w = fmaxf(fmaf(v1.w, c3, d3), 0.f);
      a00 = fmaf(v0.x, wa[4 * q + 0], a00); a01 = fmaf(v0.x, wb[4 * q + 0], a01);
      a00 = fmaf(v0.y, wa[4 * q + 1], a00); a01 = fmaf(v0.y, wb[4 * q + 1], a01);
      a00 = fmaf(v0.z, wa[4 * q + 2], a00); a01 = fmaf(v0.z, wb[4 * q + 2], a01);
      a00 = fmaf(v0.w, wa[4 * q + 3], a00); a01 = fmaf(v0.w, wb[4 * q + 3], a01);
      a10 = fmaf(v1.x, wa[4 * q + 0], a10); a11 = fmaf(v1.x, wb[4 * q + 0], a11);
      a10 = fmaf(v1.y, wa[4 * q + 1], a10); a11 = fmaf(v1.y, wb[4 * q + 1], a11);
      a10 = fmaf(v1.z, wa[4 * q + 2], a10); a11 = fmaf(v1.z, wb[4 * q + 2], a11);
      a10 = fmaf(v1.w, wa[4 * q + 3], a10); a11 = fmaf(v1.w, wb[4 * q + 3], a11);
    }
    if (t < 288) {
      *(float2*)(G1 + n * 576 + 2 * t)       = make_float2(a00, a01);
      *(float2*)(G1 + (n + 1) * 576 + 2 * t) = make_float2(a10, a11);
    } else {
      int o = 2 * (t - 288);
      *(float2*)(h1 + n * 64 + o)       = make_float2(a00 + bia, a01 + bib);
      *(float2*)(h1 + (n + 1) * 64 + o) = make_float2(a10 + bia, a11 + bib);
    }
  }
}

// ---------------------------------------------------------------------------
// K5: layer-1 edge kernel, chunked src-sorted. Wave = 16-edge chunk; G row
// (64 cols x 9) in VGPRs, reloaded only on src change.
// ---------------------------------------------------------------------------
__global__ __launch_bounds__(256) void k_edge1c(
    const int* __restrict__ srcS, const int* __restrict__ dstS,
    const float* __restrict__ eaS,
    const float* __restrict__ G1, float* __restrict__ h1)
{
  int tid = threadIdx.x;
  int o = tid & 63;
  int w = blockIdx.x * 4 + (tid >> 6);
  int p0 = w * 16;
  if (p0 >= NE) return;
  int p1 = p0 + 16; if (p1 > NE) p1 = NE;
  int scur = -1;
  float g[8] = {0,0,0,0,0,0,0,0};
  float gb = 0.f;
  for (int p = p0; p < p1; ++p) {
    int s = srcS[p];
    if (s != scur) {
      const float* gr = G1 + (size_t)s * 576;
#pragma unroll
      for (int k = 0; k < 8; ++k) g[k] = gr[k * 64 + o];
      gb = gr[512 + o];
      scur = s;
    }
    int dst = dstS[p];
    const float4* ev = (const float4*)(eaS + 8 * (size_t)p);
    float4 e0 = ev[0], e1 = ev[1];
    float m = gb;
    m = fmaf(e0.x, g[0], m); m = fmaf(e0.y, g[1], m);
    m = fmaf(e0.z, g[2], m); m = fmaf(e0.w, g[3], m);
    m = fmaf(e1.x, g[4], m); m = fmaf(e1.y, g[5], m);
    m = fmaf(e1.z, g[6], m); m = fmaf(e1.w, g[7], m);
    unsafeAtomicAdd(&h1[(size_t)dst * 64 + o], m);
  }
}

// ---------------------------------------------------------------------------
// K7: head with FUSED BN1+ReLU (reads raw h1 + st1). Thread c (0..127 per
// 2-wave group) owns output column c in regs. Sorted batch -> per-thread
// accumulator, one atomic per boundary.
// ---------------------------------------------------------------------------
__global__ __launch_bounds__(256) void k_head(
    const float* __restrict__ h1, const float* __restrict__ st1,
    const float* __restrict__ gamma1, const float* __restrict__ beta1,
    const float* __restrict__ wstT, const float* __restrict__ s_b,
    const float* __restrict__ t_b, const int* __restrict__ batch,
    float* __restrict__ out)
{
  __shared__ float sc[64], sh[64];
  int tid = threadIdx.x;
  if (tid < 64) {
    float mu  = st1[tid] * (1.0f / NN);
    float var = st1[64 + tid] * (1.0f / NN) - mu * mu;
    float s   = gamma1[tid] * rsqrtf(var + BN_EPS);
    sc[tid] = s;
    sh[tid] = beta1[tid] - mu * s;
  }
  __syncthreads();

  int c = tid & 127, g = tid >> 7;
  int n0 = blockIdx.x * 40 + g * 20;
  int n1 = n0 + 20;
  if (n0 >= NN) return;
  if (n1 > NN) n1 = NN;

  float wsr[64], wtr[64];
#pragma unroll
  for (int k = 0; k < 64; ++k) {
    wsr[k] = wstT[k * 256 + c];
    wtr[k] = wstT[k * 256 + 128 + c];
  }
  float sb = s_b[c], tb = t_b[c];

  int bcur = batch[n0];
  float facc = 0.f;
  for (int n = n0; n < n1; ++n) {
    const float4* xr = (const float4*)(h1 + (size_t)n * 64);
    float as = 0.f, at = 0.f;
#pragma unroll
    for (int q = 0; q < 16; ++q) {
      float4 xv = xr[q];
      xv.x = fmaxf(fmaf(xv.x, sc[4 * q],     sh[4 * q]),     0.f);
      xv.y = fmaxf(fmaf(xv.y, sc[4 * q + 1], sh[4 * q + 1]), 0.f);
      xv.z = fmaxf(fmaf(xv.z, sc[4 * q + 2], sh[4 * q + 2]), 0.f);
      xv.w = fmaxf(fmaf(xv.w, sc[4 * q + 3], sh[4 * q + 3]), 0.f);
      as = fmaf(xv.x, wsr[4 * q + 0], as); at = fmaf(xv.x, wtr[4 * q + 0], at);
      as = fmaf(xv.y, wsr[4 * q + 1], as); at = fmaf(xv.y, wtr[4 * q + 1], at);
      as = fmaf(xv.z, wsr[4 * q + 2], as); at = fmaf(xv.z, wtr[4 * q + 2], at);
      as = fmaf(xv.w, wsr[4 * q + 3], as); at = fmaf(xv.w, wtr[4 * q + 3], at);
    }
    float sv = fminf(30.f, fmaxf(-30.f, as + sb));
    float tv = at + tb;
    float f  = tanhf(tv) / (1.f + expf(sv));
    int b = batch[n];
    if (b != bcur) {
      unsafeAtomicAdd(&out[bcur * 128 + c], facc);
      bcur = b; facc = 0.f;
    }
    facc += f;
  }
  unsafeAtomicAdd(&out[bcur * 128 + c], facc);
}

// ---------------------------------------------------------------------------
extern "C" void kernel_launch(void* const* d_in, const int* in_sizes, int n_in,
                              void* d_out, int out_size, void* d_ws, size_t ws_size,
                              hipStream_t stream)
{
  const float* x     = (const float*)d_in[0];
  const int*   ei    = (const int*)d_in[1];
  const float* ea    = (const float*)d_in[2];
  const int*   batch = (const int*)d_in[3];
  // d_in[4] edge_batch: unused by the reference
  const float* w0    = (const float*)d_in[5];
  const float* b0    = (const float*)d_in[6];
  const float* root0 = (const float*)d_in[7];
  const float* bias0 = (const float*)d_in[8];
  const float* g0    = (const float*)d_in[9];
  const float* be0   = (const float*)d_in[10];
  const float* w1    = (const float*)d_in[11];
  const float* b1    = (const float*)d_in[12];
  const float* root1 = (const float*)d_in[13];
  const float* bias1 = (const float*)d_in[14];
  const float* g1    = (const float*)d_in[15];
  const float* be1   = (const float*)d_in[16];
  const float* s_w   = (const float*)d_in[17];
  const float* s_b   = (const float*)d_in[18];
  const float* t_w   = (const float*)d_in[19];
  const float* t_b   = (const float*)d_in[20];
  float* out = (float*)d_out;

  float* ws   = (float*)d_ws;
  float* G0   = ws;  ws += 2880000;   // N*288
  float* G1   = ws;  ws += 5760000;   // N*576
  float* h0   = ws;  ws += 320000;    // N*32
  float* h1   = ws;  ws += 640000;    // N*64
  float* st0  = ws;  ws += 64;
  float* st1  = ws;  ws += 128;
  float* wstT = ws;  ws += 16384;     // 64x256 transposed head weights
  float* wT0  = ws;  ws += 5120;      // 16x320
  float* wT1  = ws;  ws += 20480;     // 32x640
  float* eaS  = ws;  ws += 800000;    // E*8 src-sorted edge attrs
  int*   iw   = (int*)ws;
  int* deg    = iw;  iw += NN;
  int* cursor = iw;  iw += NN;
  int* srcS   = iw;  iw += NE;
  int* dstS   = iw;  iw += NE;

  hipLaunchKernelGGL(k_prep, dim3(64), dim3(256), 0, stream,
                     w0, b0, root0, w1, b1, root1, s_w, t_w,
                     wT0, wT1, wstT, st0, st1, out, deg);
  hipLaunchKernelGGL(k_node0hist, dim3(600), dim3(320), 0, stream,
                     x, wT0, bias0, G0, h0, ei, deg);
  hipLaunchKernelGGL(k_scan, dim3(1), dim3(256), 0, stream, deg, cursor);
  hipLaunchKernelGGL(k_scatter, dim3((NE + 255) / 256), dim3(256), 0, stream,
                     ei, ea, cursor, srcS, dstS, eaS);
  hipLaunchKernelGGL(k_edge0c, dim3((NE / 32 + 3) / 4), dim3(256), 0, stream,
                     srcS, dstS, eaS, G0, h0);
  hipLaunchKernelGGL(k_stats<32>, dim3(64), dim3(256), 0, stream, h0, st0);
  hipLaunchKernelGGL(k_node1, dim3(500), dim3(320), 0, stream,
                     h0, st0, g0, be0, wT1, bias1, G1, h1);
  hipLaunchKernelGGL(k_edge1c, dim3((NE / 16 + 3) / 4), dim3(256), 0, stream,
                     srcS, dstS, eaS, G1, h1);
  hipLaunchKernelGGL(k_stats<64>, dim3(128), dim3(256), 0, stream, h1, st1);
  hipLaunchKernelGGL(k_head, dim3(250), dim3(256), 0, stream,
                     h1, st1, g1, be1, wstT, s_b, t_b, batch, out);
}

// Round 7
// 232.200 us; speedup vs baseline: 1.1466x; 1.1241x over previous
//
#include <hip/hip_runtime.h>
#include <math.h>

#define NN 10000
#define NE 100000
#define BN_EPS 1e-5f

// ---------------------------------------------------------------------------
// K0: prep. Pre-transpose weights, zero out + BN-stat accumulators.
//  wT0[i*320+c]: c<256 -> w0[(i*32+(c&31))*8+(c>>5)]; c<288 -> b0; else root0
//  wT1[i*640+c]: c<512 -> w1[(i*64+(c&63))*8+(c>>6)]; c<576 -> b1; else root1
//  wstT[i*256+o]: o<128 -> s_w[o,i]; else t_w[o-128,i]
// ---------------------------------------------------------------------------
__global__ __launch_bounds__(256) void k_prep(
    const float* __restrict__ w0, const float* __restrict__ b0,
    const float* __restrict__ root0,
    const float* __restrict__ w1, const float* __restrict__ b1,
    const float* __restrict__ root1,
    const float* __restrict__ s_w, const float* __restrict__ t_w,
    float* __restrict__ wT0, float* __restrict__ wT1, float* __restrict__ wstT,
    float* __restrict__ st0, float* __restrict__ st1, float* __restrict__ out)
{
  int gid = blockIdx.x * 256 + threadIdx.x;
  int gsz = gridDim.x * 256;
  for (int idx = gid; idx < 16 * 320; idx += gsz) {
    int i = idx / 320, c = idx - i * 320;
    float v;
    if (c < 256)      v = w0[(i * 32 + (c & 31)) * 8 + (c >> 5)];
    else if (c < 288) v = b0[i * 32 + (c - 256)];
    else              v = root0[i * 32 + (c - 288)];
    wT0[idx] = v;
  }
  for (int idx = gid; idx < 32 * 640; idx += gsz) {
    int i = idx / 640, c = idx - i * 640;
    float v;
    if (c < 512)      v = w1[(i * 64 + (c & 63)) * 8 + (c >> 6)];
    else if (c < 576) v = b1[i * 64 + (c - 512)];
    else              v = root1[i * 64 + (c - 576)];
    wT1[idx] = v;
  }
  for (int idx = gid; idx < 64 * 256; idx += gsz) {
    int i = idx >> 8, o = idx & 255;
    wstT[idx] = (o < 128) ? s_w[o * 64 + i] : t_w[(o - 128) * 64 + i];
  }
  for (int idx = gid; idx < 64 * 128; idx += gsz) out[idx] = 0.f;
  if (gid < 64)  st0[gid] = 0.f;
  if (gid < 128) st1[gid] = 0.f;
}

// ---------------------------------------------------------------------------
// K1: layer-0 node kernel, register-column GEMV (thread c owns column c).
// ---------------------------------------------------------------------------
__global__ __launch_bounds__(320) void k_node0(
    const float* __restrict__ x, const float* __restrict__ wT0,
    const float* __restrict__ bias0,
    float* __restrict__ G0, float* __restrict__ h0)
{
  int c = threadIdx.x;
  float wc[16];
#pragma unroll
  for (int i = 0; i < 16; ++i) wc[i] = wT0[i * 320 + c];
  float bi = (c >= 288) ? bias0[c - 288] : 0.f;

  int n0 = blockIdx.x * 20;
  for (int n = n0; n < n0 + 20; n += 2) {
    const float4* xa = (const float4*)(x + n * 16);
    float a0 = 0.f, a1 = 0.f;
#pragma unroll
    for (int q = 0; q < 4; ++q) {
      float4 v0 = xa[q], v1 = xa[q + 4];
      a0 = fmaf(v0.x, wc[4 * q + 0], a0); a1 = fmaf(v1.x, wc[4 * q + 0], a1);
      a0 = fmaf(v0.y, wc[4 * q + 1], a0); a1 = fmaf(v1.y, wc[4 * q + 1], a1);
      a0 = fmaf(v0.z, wc[4 * q + 2], a0); a1 = fmaf(v1.z, wc[4 * q + 2], a1);
      a0 = fmaf(v0.w, wc[4 * q + 3], a0); a1 = fmaf(v1.w, wc[4 * q + 3], a1);
    }
    if (c < 288) {
      G0[n * 288 + c]       = a0;
      G0[(n + 1) * 288 + c] = a1;
    } else {
      h0[n * 32 + (c - 288)]       = a0 + bi;
      h0[(n + 1) * 32 + (c - 288)] = a1 + bi;
    }
  }
}

// ---------------------------------------------------------------------------
// K2: layer-0 edge kernel, flat. Half-wave (32 lanes) per edge; G0 rows are
// L2/L3-resident (11.5 MB), reads absorbed by cache.
// ---------------------------------------------------------------------------
__global__ __launch_bounds__(256) void k_edge0(
    const int* __restrict__ ei, const float* __restrict__ ea,
    const float* __restrict__ G0, float* __restrict__ h0)
{
  int tid = threadIdx.x;
  int e = blockIdx.x * 8 + (tid >> 5);
  if (e >= NE) return;
  int o = tid & 31;
  int src = ei[e], dst = ei[NE + e];
  const float* gr = G0 + (size_t)src * 288;
  const float* er = ea + (size_t)e * 8;
  float m = gr[256 + o];
#pragma unroll
  for (int k = 0; k < 8; ++k) m = fmaf(er[k], gr[k * 32 + o], m);
  unsafeAtomicAdd(&h0[(size_t)dst * 32 + o], m);
}

// ---------------------------------------------------------------------------
// K3/K6: per-column sum & sumsq over N rows (BN stats), atomic partials.
// ---------------------------------------------------------------------------
template <int C>
__global__ __launch_bounds__(256) void k_stats(
    const float* __restrict__ h, float* __restrict__ st)
{
  const int RPB = 256 / C;
  int tid = threadIdx.x;
  int col = tid % C, rg = tid / C;
  float s1 = 0.f, s2 = 0.f;
  int step = gridDim.x * RPB;
  for (int n = blockIdx.x * RPB + rg; n < NN; n += step) {
    float v = h[n * C + col];
    s1 += v; s2 += v * v;
  }
  __shared__ float l1[256], l2[256];
  l1[tid] = s1; l2[tid] = s2;
  __syncthreads();
  if (tid < C) {
    for (int r = 1; r < RPB; ++r) { s1 += l1[r * C + tid]; s2 += l2[r * C + tid]; }
    unsafeAtomicAdd(&st[tid], s1);
    unsafeAtomicAdd(&st[C + tid], s2);
  }
}

// ---------------------------------------------------------------------------
// K4: layer-1 node kernel with FUSED BN0+ReLU (reads raw h0 + st0).
// Thread t owns output columns {2t, 2t+1} in 64 weight VGPRs.
// ---------------------------------------------------------------------------
__global__ __launch_bounds__(320) void k_node1(
    const float* __restrict__ h0, const float* __restrict__ st0,
    const float* __restrict__ gamma0, const float* __restrict__ beta0,
    const float* __restrict__ wT1, const float* __restrict__ bias1,
    float* __restrict__ G1, float* __restrict__ h1)
{
  __shared__ float sc[32], sh[32];
  int t = threadIdx.x;
  if (t < 32) {
    float mu  = st0[t] * (1.0f / NN);
    float var = st0[32 + t] * (1.0f / NN) - mu * mu;
    float s   = gamma0[t] * rsqrtf(var + BN_EPS);
    sc[t] = s;
    sh[t] = beta0[t] - mu * s;
  }
  __syncthreads();

  float wa[32], wb[32];
#pragma unroll
  for (int i = 0; i < 32; ++i) {
    float2 w2 = *(const float2*)(wT1 + i * 640 + 2 * t);
    wa[i] = w2.x; wb[i] = w2.y;
  }
  float bia = 0.f, bib = 0.f;
  if (t >= 288) { bia = bias1[2 * (t - 288)]; bib = bias1[2 * (t - 288) + 1]; }

  int n0 = blockIdx.x * 20;
  for (int n = n0; n < n0 + 20; n += 2) {
    const float4* xa = (const float4*)(h0 + n * 32);
    float a00 = 0.f, a01 = 0.f, a10 = 0.f, a11 = 0.f;
#pragma unroll
    for (int q = 0; q < 8; ++q) {
      float4 v0 = xa[q], v1 = xa[q + 8];  // rows n and n+1, cols 4q..4q+3
      float c0 = sc[4 * q], c1 = sc[4 * q + 1], c2 = sc[4 * q + 2], c3 = sc[4 * q + 3];
      float d0 = sh[4 * q], d1 = sh[4 * q + 1], d2 = sh[4 * q + 2], d3 = sh[4 * q + 3];
      v0.x = fmaxf(fmaf(v0.x, c0, d0), 0.f); v1.x = fmaxf(fmaf(v1.x, c0, d0), 0.f);
      v0.y = fmaxf(fmaf(v0.y, c1, d1), 0.f); v1.y = fmaxf(fmaf(v1.y, c1, d1), 0.f);
      v0.z = fmaxf(fmaf(v0.z, c2, d2), 0.f); v1.z = fmaxf(fmaf(v1.z, c2, d2), 0.f);
      v0.w = fmaxf(fmaf(v0.w, c3, d3), 0.f); v1.w = fmaxf(fmaf(v1.w, c3, d3), 0.f);
      a00 = fmaf(v0.x, wa[4 * q + 0], a00); a01 = fmaf(v0.x, wb[4 * q + 0], a01);
      a00 = fmaf(v0.y, wa[4 * q + 1], a00); a01 = fmaf(v0.y, wb[4 * q + 1], a01);
      a00 = fmaf(v0.z, wa[4 * q + 2], a00); a01 = fmaf(v0.z, wb[4 * q + 2], a01);
      a00 = fmaf(v0.w, wa[4 * q + 3], a00); a01 = fmaf(v0.w, wb[4 * q + 3], a01);
      a10 = fmaf(v1.x, wa[4 * q + 0], a10); a11 = fmaf(v1.x, wb[4 * q + 0], a11);
      a10 = fmaf(v1.y, wa[4 * q + 1], a10); a11 = fmaf(v1.y, wb[4 * q + 1], a11);
      a10 = fmaf(v1.z, wa[4 * q + 2], a10); a11 = fmaf(v1.z, wb[4 * q + 2], a11);
      a10 = fmaf(v1.w, wa[4 * q + 3], a10); a11 = fmaf(v1.w, wb[4 * q + 3], a11);
    }
    if (t < 288) {
      *(float2*)(G1 + n * 576 + 2 * t)       = make_float2(a00, a01);
      *(float2*)(G1 + (n + 1) * 576 + 2 * t) = make_float2(a10, a11);
    } else {
      int o = 2 * (t - 288);
      *(float2*)(h1 + n * 64 + o)       = make_float2(a00 + bia, a01 + bib);
      *(float2*)(h1 + (n + 1) * 64 + o) = make_float2(a10 + bia, a11 + bib);
    }
  }
}

// ---------------------------------------------------------------------------
// K5: layer-1 edge kernel, flat. One wave (64 lanes) per edge; G1 rows
// (23 MB) L2/L3-resident.
// ---------------------------------------------------------------------------
__global__ __launch_bounds__(256) void k_edge1(
    const int* __restrict__ ei, const float* __restrict__ ea,
    const float* __restrict__ G1, float* __restrict__ h1)
{
  int tid = threadIdx.x;
  int e = blockIdx.x * 4 + (tid >> 6);
  if (e >= NE) return;
  int o = tid & 63;
  int src = ei[e], dst = ei[NE + e];
  const float* gr = G1 + (size_t)src * 576;
  const float* er = ea + (size_t)e * 8;
  float m = gr[512 + o];
#pragma unroll
  for (int k = 0; k < 8; ++k) m = fmaf(er[k], gr[k * 64 + o], m);
  unsafeAtomicAdd(&h1[(size_t)dst * 64 + o], m);
}

// ---------------------------------------------------------------------------
// K7: head with FUSED BN1+ReLU (reads raw h1 + st1). Thread c (0..127 per
// 2-wave group) owns output column c in regs. Sorted batch -> per-thread
// accumulator, one atomic per boundary.
// ---------------------------------------------------------------------------
__global__ __launch_bounds__(256) void k_head(
    const float* __restrict__ h1, const float* __restrict__ st1,
    const float* __restrict__ gamma1, const float* __restrict__ beta1,
    const float* __restrict__ wstT, const float* __restrict__ s_b,
    const float* __restrict__ t_b, const int* __restrict__ batch,
    float* __restrict__ out)
{
  __shared__ float sc[64], sh[64];
  int tid = threadIdx.x;
  if (tid < 64) {
    float mu  = st1[tid] * (1.0f / NN);
    float var = st1[64 + tid] * (1.0f / NN) - mu * mu;
    float s   = gamma1[tid] * rsqrtf(var + BN_EPS);
    sc[tid] = s;
    sh[tid] = beta1[tid] - mu * s;
  }
  __syncthreads();

  int c = tid & 127, g = tid >> 7;
  int n0 = blockIdx.x * 40 + g * 20;
  int n1 = n0 + 20;
  if (n0 >= NN) return;
  if (n1 > NN) n1 = NN;

  float wsr[64], wtr[64];
#pragma unroll
  for (int k = 0; k < 64; ++k) {
    wsr[k] = wstT[k * 256 + c];
    wtr[k] = wstT[k * 256 + 128 + c];
  }
  float sb = s_b[c], tb = t_b[c];

  int bcur = batch[n0];
  float facc = 0.f;
  for (int n = n0; n < n1; ++n) {
    const float4* xr = (const float4*)(h1 + (size_t)n * 64);
    float as = 0.f, at = 0.f;
#pragma unroll
    for (int q = 0; q < 16; ++q) {
      float4 xv = xr[q];
      xv.x = fmaxf(fmaf(xv.x, sc[4 * q],     sh[4 * q]),     0.f);
      xv.y = fmaxf(fmaf(xv.y, sc[4 * q + 1], sh[4 * q + 1]), 0.f);
      xv.z = fmaxf(fmaf(xv.z, sc[4 * q + 2], sh[4 * q + 2]), 0.f);
      xv.w = fmaxf(fmaf(xv.w, sc[4 * q + 3], sh[4 * q + 3]), 0.f);
      as = fmaf(xv.x, wsr[4 * q + 0], as); at = fmaf(xv.x, wtr[4 * q + 0], at);
      as = fmaf(xv.y, wsr[4 * q + 1], as); at = fmaf(xv.y, wtr[4 * q + 1], at);
      as = fmaf(xv.z, wsr[4 * q + 2], as); at = fmaf(xv.z, wtr[4 * q + 2], at);
      as = fmaf(xv.w, wsr[4 * q + 3], as); at = fmaf(xv.w, wtr[4 * q + 3], at);
    }
    float sv = fminf(30.f, fmaxf(-30.f, as + sb));
    float tv = at + tb;
    float f  = tanhf(tv) / (1.f + expf(sv));
    int b = batch[n];
    if (b != bcur) {
      unsafeAtomicAdd(&out[bcur * 128 + c], facc);
      bcur = b; facc = 0.f;
    }
    facc += f;
  }
  unsafeAtomicAdd(&out[bcur * 128 + c], facc);
}

// ---------------------------------------------------------------------------
extern "C" void kernel_launch(void* const* d_in, const int* in_sizes, int n_in,
                              void* d_out, int out_size, void* d_ws, size_t ws_size,
                              hipStream_t stream)
{
  const float* x     = (const float*)d_in[0];
  const int*   ei    = (const int*)d_in[1];
  const float* ea    = (const float*)d_in[2];
  const int*   batch = (const int*)d_in[3];
  // d_in[4] edge_batch: unused by the reference
  const float* w0    = (const float*)d_in[5];
  const float* b0    = (const float*)d_in[6];
  const float* root0 = (const float*)d_in[7];
  const float* bias0 = (const float*)d_in[8];
  const float* g0    = (const float*)d_in[9];
  const float* be0   = (const float*)d_in[10];
  const float* w1    = (const float*)d_in[11];
  const float* b1    = (const float*)d_in[12];
  const float* root1 = (const float*)d_in[13];
  const float* bias1 = (const float*)d_in[14];
  const float* g1    = (const float*)d_in[15];
  const float* be1   = (const float*)d_in[16];
  const float* s_w   = (const float*)d_in[17];
  const float* s_b   = (const float*)d_in[18];
  const float* t_w   = (const float*)d_in[19];
  const float* t_b   = (const float*)d_in[20];
  float* out = (float*)d_out;

  float* ws   = (float*)d_ws;
  float* G0   = ws;  ws += 2880000;   // N*288
  float* G1   = ws;  ws += 5760000;   // N*576
  float* h0   = ws;  ws += 320000;    // N*32
  float* h1   = ws;  ws += 640000;    // N*64
  float* st0  = ws;  ws += 64;
  float* st1  = ws;  ws += 128;
  float* wstT = ws;  ws += 16384;     // 64x256 transposed head weights
  float* wT0  = ws;  ws += 5120;      // 16x320
  float* wT1  = ws;  ws += 20480;     // 32x640

  hipLaunchKernelGGL(k_prep, dim3(64), dim3(256), 0, stream,
                     w0, b0, root0, w1, b1, root1, s_w, t_w,
                     wT0, wT1, wstT, st0, st1, out);
  hipLaunchKernelGGL(k_node0, dim3(500), dim3(320), 0, stream,
                     x, wT0, bias0, G0, h0);
  hipLaunchKernelGGL(k_edge0, dim3((NE + 7) / 8), dim3(256), 0, stream,
                     ei, ea, G0, h0);
  hipLaunchKernelGGL(k_stats<32>, dim3(64), dim3(256), 0, stream, h0, st0);
  hipLaunchKernelGGL(k_node1, dim3(500), dim3(320), 0, stream,
                     h0, st0, g0, be0, wT1, bias1, G1, h1);
  hipLaunchKernelGGL(k_edge1, dim3((NE + 3) / 4), dim3(256), 0, stream,
                     ei, ea, G1, h1);
  hipLaunchKernelGGL(k_stats<64>, dim3(128), dim3(256), 0, stream, h1, st1);
  hipLaunchKernelGGL(k_head, dim3(250), dim3(256), 0, stream,
                     h1, st1, g1, be1, wstT, s_b, t_b, batch, out);
}